// Round 1
// baseline (50.269 us; speedup 1.0000x reference)
//
#include <hip/hip_runtime.h>
#include <math.h>

#define NT 8192
#define NS 8192
#define C 512
#define THRESH 0.01f

// ---------------- row argmax for target: mask/lab to d_out, loss + int lab to ws ----
__global__ __launch_bounds__(256) void stc_rowmax_t(
    const float* __restrict__ td, float* __restrict__ out_mask,
    float* __restrict__ out_lab, float* __restrict__ loss, int* __restrict__ labi)
{
    int wave = threadIdx.x >> 6;
    int lane = threadIdx.x & 63;
    int row = blockIdx.x * 4 + wave;
    if (row >= NT) return;
    const float* p = td + (size_t)row * C;
    float best = -1.0f; int bi = 0;
#pragma unroll
    for (int h = 0; h < 2; ++h) {
        int col = h * 256 + lane * 4;
        float4 v = *reinterpret_cast<const float4*>(p + col);
        if (v.x > best) { best = v.x; bi = col; }
        if (v.y > best) { best = v.y; bi = col + 1; }
        if (v.z > best) { best = v.z; bi = col + 2; }
        if (v.w > best) { best = v.w; bi = col + 3; }
    }
#pragma unroll
    for (int off = 32; off; off >>= 1) {
        float ov = __shfl_down(best, off);
        int   oi = __shfl_down(bi, off);
        if (ov > best || (ov == best && oi < bi)) { best = ov; bi = oi; }
    }
    if (lane == 0) {
        out_mask[row] = (best > THRESH) ? 1.0f : 0.0f;
        out_lab[row] = (float)bi;
        loss[row] = -logf(best);
        labi[row] = bi;
    }
}

// ---------------- row argmax for source: labm = mask ? lab : -1 --------------------
__global__ __launch_bounds__(256) void stc_rowmax_s(
    const float* __restrict__ sd, int* __restrict__ labm)
{
    int wave = threadIdx.x >> 6;
    int lane = threadIdx.x & 63;
    int row = blockIdx.x * 4 + wave;
    if (row >= NS) return;
    const float* p = sd + (size_t)row * C;
    float best = -1.0f; int bi = 0;
#pragma unroll
    for (int h = 0; h < 2; ++h) {
        int col = h * 256 + lane * 4;
        float4 v = *reinterpret_cast<const float4*>(p + col);
        if (v.x > best) { best = v.x; bi = col; }
        if (v.y > best) { best = v.y; bi = col + 1; }
        if (v.z > best) { best = v.z; bi = col + 2; }
        if (v.w > best) { best = v.w; bi = col + 3; }
    }
#pragma unroll
    for (int off = 32; off; off >>= 1) {
        float ov = __shfl_down(best, off);
        int   oi = __shfl_down(bi, off);
        if (ov > best || (ov == best && oi < bi)) { best = ov; bi = oi; }
    }
    if (lane == 0) {
        labm[row] = (best > THRESH) ? bi : -1;
    }
}

// ---------------- build per-class column sums G[c][:] (deterministic, no atomics) --
// One wave per (class, row-chunk). Ballot over 64 labels at a time; matched rows
// processed in ascending-row order -> deterministic fp accumulation.
__global__ __launch_bounds__(64) void stc_build_g(
    const float* __restrict__ sd, const int* __restrict__ labm,
    float* __restrict__ gpart, int rows_per_chunk)
{
    const int c = blockIdx.x;
    const int chunk = blockIdx.y;
    const int lane = threadIdx.x;
    const int base0 = chunk * rows_per_chunk;
    float a0 = 0, a1 = 0, a2 = 0, a3 = 0, b0 = 0, b1 = 0, b2 = 0, b3 = 0;
    for (int base = base0; base < base0 + rows_per_chunk; base += 64) {
        int l = labm[base + lane];
        unsigned long long mb = __ballot(l == c);
        while (mb) {
            int b = __ffsll(mb) - 1;
            mb &= mb - 1;
            const float* sp = sd + (size_t)(base + b) * C;
            float4 v0 = *reinterpret_cast<const float4*>(sp + lane * 4);
            float4 v1 = *reinterpret_cast<const float4*>(sp + 256 + lane * 4);
            a0 += v0.x; a1 += v0.y; a2 += v0.z; a3 += v0.w;
            b0 += v1.x; b1 += v1.y; b2 += v1.z; b3 += v1.w;
        }
    }
    float* gp = gpart + ((size_t)chunk * C + c) * C;
    *reinterpret_cast<float4*>(gp + lane * 4)       = make_float4(a0, a1, a2, a3);
    *reinterpret_cast<float4*>(gp + 256 + lane * 4) = make_float4(b0, b1, b2, b3);
}

// ---------------- reduce chunk partials ------------------------------------------
__global__ __launch_bounds__(256) void stc_reduce_g(
    const float4* __restrict__ gpart, float4* __restrict__ g, int chunks)
{
    int i = blockIdx.x * 256 + threadIdx.x;  // over C*C/4
    float4 s = gpart[i];
    for (int k = 1; k < chunks; ++k) {
        float4 v = gpart[(size_t)k * (C * C / 4) + i];
        s.x += v.x; s.y += v.y; s.z += v.z; s.w += v.w;
    }
    g[i] = s;
}

// ---------------- score[i] = dot(td[i], G[lab_t[i]]) ------------------------------
__global__ __launch_bounds__(256) void stc_score(
    const float* __restrict__ td, const float* __restrict__ G,
    const int* __restrict__ labi, float* __restrict__ score)
{
    int wave = threadIdx.x >> 6;
    int lane = threadIdx.x & 63;
    int row = blockIdx.x * 4 + wave;
    if (row >= NT) return;
    const float* a = td + (size_t)row * C;
    const float* g = G + (size_t)labi[row] * C;
    float acc = 0.0f;
#pragma unroll
    for (int h = 0; h < 2; ++h) {
        int col = h * 256 + lane * 4;
        float4 x = *reinterpret_cast<const float4*>(a + col);
        float4 y = *reinterpret_cast<const float4*>(g + col);
        acc += x.x * y.x + x.y * y.y + x.z * y.z + x.w * y.w;
    }
#pragma unroll
    for (int off = 32; off; off >>= 1) acc += __shfl_down(acc, off);
    if (lane == 0) score[row] = acc;
}

// ---------------- masked softmax stats + weighted loss (single block) -------------
__global__ __launch_bounds__(1024) void stc_stats(
    const float* __restrict__ score, const float* __restrict__ mask_f,
    const float* __restrict__ loss, float* __restrict__ scal,
    float* __restrict__ out0)
{
    __shared__ float red[1024];
    int t = threadIdx.x;
    float vmax = -1e30f;
    for (int i = t; i < NT; i += 1024) {
        float v = (mask_f[i] != 0.0f) ? score[i] : -1e30f;
        vmax = fmaxf(vmax, v);
    }
    red[t] = vmax; __syncthreads();
    for (int s = 512; s; s >>= 1) {
        if (t < s) red[t] = fmaxf(red[t], red[t + s]);
        __syncthreads();
    }
    float m = red[0]; __syncthreads();

    float se = 0.0f, sle = 0.0f, cnt = 0.0f;
    for (int i = t; i < NT; i += 1024) {
        bool msk = mask_f[i] != 0.0f;
        float v = msk ? score[i] : -1e30f;
        float e = expf(v - m);
        se += e;
        if (msk) { sle += loss[i] * e; cnt += 1.0f; }
    }
    red[t] = se; __syncthreads();
    for (int s = 512; s; s >>= 1) { if (t < s) red[t] += red[t + s]; __syncthreads(); }
    float se_tot = red[0]; __syncthreads();
    red[t] = sle; __syncthreads();
    for (int s = 512; s; s >>= 1) { if (t < s) red[t] += red[t + s]; __syncthreads(); }
    float sle_tot = red[0]; __syncthreads();
    red[t] = cnt; __syncthreads();
    for (int s = 512; s; s >>= 1) { if (t < s) red[t] += red[t + s]; __syncthreads(); }
    float cnt_tot = red[0];

    if (t == 0) {
        scal[0] = m;
        scal[1] = se_tot;
        float c = fmaxf(cnt_tot, 1.0f);
        out0[0] = (sle_tot / se_tot) / c;
    }
}

// ---------------- weights[i] ------------------------------------------------------
__global__ __launch_bounds__(256) void stc_weights(
    const float* __restrict__ score, const float* __restrict__ mask_f,
    const float* __restrict__ scal, float* __restrict__ out_w)
{
    int i = blockIdx.x * 256 + threadIdx.x;
    if (i >= NT) return;
    float m = scal[0];
    float se = scal[1];
    float v = (mask_f[i] != 0.0f) ? score[i] : -1e30f;
    out_w[i] = expf(v - m) / se;
}

extern "C" void kernel_launch(void* const* d_in, const int* in_sizes, int n_in,
                              void* d_out, int out_size, void* d_ws, size_t ws_size,
                              hipStream_t stream) {
    const float* td = (const float*)d_in[0];
    const float* sd = (const float*)d_in[1];
    float* out = (float*)d_out;
    float* out_loss = out;              // [1]
    float* out_mask = out + 1;          // [NT]
    float* out_lab  = out + 1 + NT;     // [NT]
    float* out_w    = out + 1 + 2 * NT; // [NT]

    char* ws = (char*)d_ws;
    float* loss  = (float*)(ws + 0);                 // NT floats
    float* score = (float*)(ws + 32768);             // NT floats
    int*   labm  = (int*)  (ws + 65536);             // NS ints
    int*   labi  = (int*)  (ws + 98304);             // NT ints
    float* scal  = (float*)(ws + 131072);            // 2 floats
    float* G     = (float*)(ws + 132096);            // C*C floats (1 MB)
    float* Gpart = (float*)(ws + 132096 + (size_t)C * C * 4);

    int chunks = 4;
    size_t need4 = 132096 + (size_t)C * C * 4 * (1 + 4);
    if (ws_size < need4) { chunks = 1; Gpart = G; }
    int rows_per_chunk = NS / chunks;

    stc_rowmax_t<<<NT / 4, 256, 0, stream>>>(td, out_mask, out_lab, loss, labi);
    stc_rowmax_s<<<NS / 4, 256, 0, stream>>>(sd, labm);
    stc_build_g<<<dim3(C, chunks), 64, 0, stream>>>(sd, labm, Gpart, rows_per_chunk);
    if (chunks > 1) {
        stc_reduce_g<<<(C * C / 4) / 256, 256, 0, stream>>>((const float4*)Gpart, (float4*)G, chunks);
    }
    stc_score<<<NT / 4, 256, 0, stream>>>(td, G, labi, score);
    stc_stats<<<1, 1024, 0, stream>>>(score, out_mask, loss, scal, out_loss);
    stc_weights<<<NT / 256, 256, 0, stream>>>(score, out_mask, scal, out_w);
}

// Round 2
// 50.183 us; speedup vs baseline: 1.0017x; 1.0017x over previous
//
#include <hip/hip_runtime.h>
#include <math.h>

#define NT 8192
#define NS 8192
#define C 512
#define THRESH 0.01f

// ---------------- K1: row argmax for BOTH matrices in one dispatch ----------------
// waves [0, NT) -> target rows (mask/lab to d_out, loss + int lab to ws)
// waves [NT, NT+NS) -> source rows (labm = mask ? lab : -1)
__global__ __launch_bounds__(256) void stc_rowmax(
    const float* __restrict__ td, const float* __restrict__ sd,
    float* __restrict__ out_mask, float* __restrict__ out_lab,
    float* __restrict__ loss, int* __restrict__ labi, int* __restrict__ labm)
{
    int wave = threadIdx.x >> 6;
    int lane = threadIdx.x & 63;
    int gw = blockIdx.x * 4 + wave;          // [0, NT+NS)
    bool is_t = gw < NT;
    int row = is_t ? gw : gw - NT;
    const float* p = (is_t ? td : sd) + (size_t)row * C;

    float best = -1.0f; int bi = 0;
#pragma unroll
    for (int h = 0; h < 2; ++h) {
        int col = h * 256 + lane * 4;
        float4 v = *reinterpret_cast<const float4*>(p + col);
        if (v.x > best) { best = v.x; bi = col; }
        if (v.y > best) { best = v.y; bi = col + 1; }
        if (v.z > best) { best = v.z; bi = col + 2; }
        if (v.w > best) { best = v.w; bi = col + 3; }
    }
#pragma unroll
    for (int off = 32; off; off >>= 1) {
        float ov = __shfl_down(best, off);
        int   oi = __shfl_down(bi, off);
        if (ov > best || (ov == best && oi < bi)) { best = ov; bi = oi; }
    }
    if (lane == 0) {
        if (is_t) {
            out_mask[row] = (best > THRESH) ? 1.0f : 0.0f;
            out_lab[row] = (float)bi;
            loss[row] = -logf(best);
            labi[row] = bi;
        } else {
            labm[row] = (best > THRESH) ? bi : -1;
        }
    }
}

// ---------------- K2: per-class column sums Gpart[chunk][c][:] (deterministic) ----
// One wave per (class, row-chunk). Ballot over 64 labels at a time; matched rows
// processed in ascending-row order -> deterministic fp accumulation.
__global__ __launch_bounds__(64) void stc_build_g(
    const float* __restrict__ sd, const int* __restrict__ labm,
    float* __restrict__ gpart, int rows_per_chunk)
{
    const int c = blockIdx.x;
    const int chunk = blockIdx.y;
    const int lane = threadIdx.x;
    const int base0 = chunk * rows_per_chunk;
    float a0 = 0, a1 = 0, a2 = 0, a3 = 0, b0 = 0, b1 = 0, b2 = 0, b3 = 0;
    for (int base = base0; base < base0 + rows_per_chunk; base += 64) {
        int l = labm[base + lane];
        unsigned long long mb = __ballot(l == c);
        while (mb) {
            int b = __ffsll(mb) - 1;
            mb &= mb - 1;
            const float* sp = sd + (size_t)(base + b) * C;
            float4 v0 = *reinterpret_cast<const float4*>(sp + lane * 4);
            float4 v1 = *reinterpret_cast<const float4*>(sp + 256 + lane * 4);
            a0 += v0.x; a1 += v0.y; a2 += v0.z; a3 += v0.w;
            b0 += v1.x; b1 += v1.y; b2 += v1.z; b3 += v1.w;
        }
    }
    float* gp = gpart + ((size_t)chunk * C + c) * C;
    *reinterpret_cast<float4*>(gp + lane * 4)       = make_float4(a0, a1, a2, a3);
    *reinterpret_cast<float4*>(gp + 256 + lane * 4) = make_float4(b0, b1, b2, b3);
}

// ---------------- K3: score[i] = sum_k dot(td[i], Gpart[k][lab_t[i]]) -------------
__global__ __launch_bounds__(256) void stc_score(
    const float* __restrict__ td, const float* __restrict__ gpart,
    const int* __restrict__ labi, float* __restrict__ score, int chunks)
{
    int wave = threadIdx.x >> 6;
    int lane = threadIdx.x & 63;
    int row = blockIdx.x * 4 + wave;
    if (row >= NT) return;
    const float* a = td + (size_t)row * C;
    int lab = labi[row];

    float4 x0 = *reinterpret_cast<const float4*>(a + lane * 4);
    float4 x1 = *reinterpret_cast<const float4*>(a + 256 + lane * 4);

    float acc = 0.0f;
    for (int k = 0; k < chunks; ++k) {
        const float* g = gpart + ((size_t)k * C + lab) * C;
        float4 y0 = *reinterpret_cast<const float4*>(g + lane * 4);
        float4 y1 = *reinterpret_cast<const float4*>(g + 256 + lane * 4);
        acc += x0.x * y0.x + x0.y * y0.y + x0.z * y0.z + x0.w * y0.w;
        acc += x1.x * y1.x + x1.y * y1.y + x1.z * y1.z + x1.w * y1.w;
    }
#pragma unroll
    for (int off = 32; off; off >>= 1) acc += __shfl_down(acc, off);
    if (lane == 0) score[row] = acc;
}

// ---------------- K4: masked softmax stats + weighted loss + weights (1 block) ----
__global__ __launch_bounds__(1024) void stc_stats_weights(
    const float* __restrict__ score, const float* __restrict__ mask_f,
    const float* __restrict__ loss, float* __restrict__ out0,
    float* __restrict__ out_w)
{
    __shared__ float red[1024];
    int t = threadIdx.x;
    float vmax = -1e30f;
    for (int i = t; i < NT; i += 1024) {
        float v = (mask_f[i] != 0.0f) ? score[i] : -1e30f;
        vmax = fmaxf(vmax, v);
    }
    red[t] = vmax; __syncthreads();
    for (int s = 512; s; s >>= 1) {
        if (t < s) red[t] = fmaxf(red[t], red[t + s]);
        __syncthreads();
    }
    float m = red[0]; __syncthreads();

    float se = 0.0f, sle = 0.0f, cnt = 0.0f;
    for (int i = t; i < NT; i += 1024) {
        bool msk = mask_f[i] != 0.0f;
        float v = msk ? score[i] : -1e30f;
        float e = expf(v - m);
        se += e;
        if (msk) { sle += loss[i] * e; cnt += 1.0f; }
    }
    red[t] = se; __syncthreads();
    for (int s = 512; s; s >>= 1) { if (t < s) red[t] += red[t + s]; __syncthreads(); }
    float se_tot = red[0]; __syncthreads();
    red[t] = sle; __syncthreads();
    for (int s = 512; s; s >>= 1) { if (t < s) red[t] += red[t + s]; __syncthreads(); }
    float sle_tot = red[0]; __syncthreads();
    red[t] = cnt; __syncthreads();
    for (int s = 512; s; s >>= 1) { if (t < s) red[t] += red[t + s]; __syncthreads(); }
    float cnt_tot = red[0];

    // weights (m, se_tot live in registers; no extra dispatch)
    for (int i = t; i < NT; i += 1024) {
        float v = (mask_f[i] != 0.0f) ? score[i] : -1e30f;
        out_w[i] = expf(v - m) / se_tot;
    }
    if (t == 0) {
        out0[0] = (sle_tot / se_tot) / fmaxf(cnt_tot, 1.0f);
    }
}

extern "C" void kernel_launch(void* const* d_in, const int* in_sizes, int n_in,
                              void* d_out, int out_size, void* d_ws, size_t ws_size,
                              hipStream_t stream) {
    const float* td = (const float*)d_in[0];
    const float* sd = (const float*)d_in[1];
    float* out = (float*)d_out;
    float* out_loss = out;              // [1]
    float* out_mask = out + 1;          // [NT]
    float* out_lab  = out + 1 + NT;     // [NT]
    float* out_w    = out + 1 + 2 * NT; // [NT]

    char* ws = (char*)d_ws;
    float* loss  = (float*)(ws + 0);                 // NT floats
    float* score = (float*)(ws + 32768);             // NT floats
    int*   labm  = (int*)  (ws + 65536);             // NS ints
    int*   labi  = (int*)  (ws + 98304);             // NT ints
    float* Gpart = (float*)(ws + 131072);            // chunks * C*C floats

    int chunks = 4;
    if (ws_size < 131072 + (size_t)4 * C * C * 4) {
        chunks = (ws_size >= 131072 + (size_t)2 * C * C * 4) ? 2 : 1;
    }
    int rows_per_chunk = NS / chunks;

    stc_rowmax<<<(NT + NS) / 4, 256, 0, stream>>>(td, sd, out_mask, out_lab, loss, labi, labm);
    stc_build_g<<<dim3(C, chunks), 64, 0, stream>>>(sd, labm, Gpart, rows_per_chunk);
    stc_score<<<NT / 4, 256, 0, stream>>>(td, Gpart, labi, score, chunks);
    stc_stats_weights<<<1, 1024, 0, stream>>>(score, out_mask, loss, out_loss, out_w);
}